// Round 14
// baseline (347.167 us; speedup 1.0000x reference)
//
#include <hip/hip_runtime.h>
#include <hip/hip_bf16.h>
#include <stdint.h>
#include <stddef.h>

#define DI __device__ __forceinline__

typedef unsigned short u16;
typedef float f32x4 __attribute__((ext_vector_type(4)));
typedef short bf16x8 __attribute__((ext_vector_type(8)));
typedef u16 u16x4 __attribute__((ext_vector_type(4)));

constexpr int Mm = 8192;
constexpr int Dd = 1024;
constexpr float LOG2E = 1.44269504088896f;

DI u16 bf(float f) {
  __hip_bfloat16 h = __float2bfloat16(f);
  return *reinterpret_cast<u16*>(&h);
}

DI float b2f(short s) {
  union { float f; unsigned u; } v;
  v.u = ((unsigned)(unsigned short)s) << 16;
  return v.f;
}

DI f32x4 mfma16(bf16x8 a, bf16x8 b, f32x4 c) {
  return __builtin_amdgcn_mfma_f32_16x16x32_bf16(a, b, c, 0, 0, 0);
}

DI void gload16(const u16* g, u16* l) {
  __builtin_amdgcn_global_load_lds(
      (const __attribute__((address_space(1))) void*)(g),
      (__attribute__((address_space(3))) void*)(l), 16, 0, 0);
}

// ---------------- prep: cvt x | pb->bf16*log2e | transpose 4 W ----------------
__global__ __launch_bounds__(256) void k_prep(const float* __restrict__ x,
                                              u16* __restrict__ xb,
                                              const float* __restrict__ pb,
                                              u16* __restrict__ pbb,
                                              const float* __restrict__ W0,
                                              const float* __restrict__ W1,
                                              const float* __restrict__ W2,
                                              const float* __restrict__ W3,
                                              u16* __restrict__ T0,
                                              u16* __restrict__ T1,
                                              u16* __restrict__ T2,
                                              u16* __restrict__ T3) {
  __shared__ float t[32][33];
  const int bid = blockIdx.x;
  const int tid = threadIdx.x;
  if (bid < 8192) {
    size_t i = (size_t)bid * 256 + tid;
    float4 v = *(const float4*)(x + i * 4);
    u16x4 r;
    r.x = bf(v.x); r.y = bf(v.y); r.z = bf(v.z); r.w = bf(v.w);
    *(u16x4*)(xb + i * 4) = r;
  } else if (bid < 9216) {
    size_t i = (size_t)(bid - 8192) * 256 + tid;
    float4 v = *(const float4*)(pb + i * 4);
    u16x4 r;
    r.x = bf(v.x * LOG2E); r.y = bf(v.y * LOG2E);
    r.z = bf(v.z * LOG2E); r.w = bf(v.w * LOG2E);
    *(u16x4*)(pbb + i * 4) = r;
  } else {
    const int tt = bid - 9216;
    const int z = tt >> 10;
    const int rem = tt & 1023;
    const float* W;
    u16* T;
    switch (z) {
      case 0: W = W0; T = T0; break;
      case 1: W = W1; T = T1; break;
      case 2: W = W2; T = T2; break;
      default: W = W3; T = T3; break;
    }
    const int bx = (rem & 31) * 32;
    const int by = (rem >> 5) * 32;
    const int tx = tid & 31, ty = tid >> 5;
#pragma unroll
    for (int i = 0; i < 4; ++i)
      t[ty + i * 8][tx] = W[(size_t)(bx + ty + i * 8) * 1024 + by + tx];
    __syncthreads();
#pragma unroll
    for (int i = 0; i < 4; ++i)
      T[(size_t)(by + ty + i * 8) * 1024 + bx + tx] = bf(t[tx][ty + i * 8]);
  }
}

// ---------------- QKV mega-GEMM: z=0 Q, z=1 K, z=2 V(transposed) ----------------
__global__ __launch_bounds__(256) void k_gemm_qkv(const u16* __restrict__ A,
                                                  const u16* __restrict__ wqT,
                                                  const u16* __restrict__ wkT,
                                                  const u16* __restrict__ wvT,
                                                  const float* __restrict__ bq,
                                                  const float* __restrict__ bk,
                                                  const float* __restrict__ bv,
                                                  u16* __restrict__ qo,
                                                  u16* __restrict__ ko,
                                                  u16* __restrict__ vo) {
  __shared__ __align__(16) u16 smem[2 * 128 * 64];
  u16* As = smem;
  u16* Bs = smem + 128 * 64;
  const int mode = blockIdx.z;
  const u16* WT = mode == 0 ? wqT : (mode == 1 ? wkT : wvT);
  const float* bias = mode == 0 ? bq : (mode == 1 ? bk : bv);
  const int tid = threadIdx.x;
  const int lane = tid & 63;
  const int wave = tid >> 6;
  const int brow = blockIdx.y * 128;
  const int bcol = blockIdx.x * 128;
  const int wr = (wave >> 1) * 64;
  const int wc = (wave & 1) * 64;
  const int l15 = lane & 15, l4 = lane >> 4;

  f32x4 acc[4][4] = {};
  const int crow0 = tid >> 3;
  const int kpos = (tid & 7) * 8;

  for (int t = 0; t < 16; ++t) {
    const int k0 = t * 64;
#pragma unroll
    for (int r = 0; r < 4; ++r) {
      int crow = r * 32 + crow0;
      u16* ldsbase_a = As + ((r * 256 + wave * 64) << 3);
      u16* ldsbase_b = Bs + ((r * 256 + wave * 64) << 3);
      gload16(A + (size_t)(brow + crow) * 1024 + k0 + kpos, ldsbase_a);
      gload16(WT + (size_t)(bcol + crow) * 1024 + k0 + kpos, ldsbase_b);
    }
    __syncthreads();
#pragma unroll
    for (int kk = 0; kk < 2; ++kk) {
      bf16x8 af[4], bg[4];
      const int kb = kk * 32 + l4 * 8;
#pragma unroll
      for (int mt = 0; mt < 4; ++mt)
        af[mt] = *(const bf16x8*)(As + (wr + mt * 16 + l15) * 64 + kb);
#pragma unroll
      for (int nt = 0; nt < 4; ++nt)
        bg[nt] = *(const bf16x8*)(Bs + (wc + nt * 16 + l15) * 64 + kb);
#pragma unroll
      for (int mt = 0; mt < 4; ++mt)
#pragma unroll
        for (int nt = 0; nt < 4; ++nt)
          acc[mt][nt] = mfma16(af[mt], bg[nt], acc[mt][nt]);
    }
    __syncthreads();
  }

  if (mode == 2) {
#pragma unroll
    for (int nt = 0; nt < 4; ++nt) {
      int dl = wc + nt * 16 + l15;
      float bvv = bias[bcol + dl];
#pragma unroll
      for (int mt = 0; mt < 4; ++mt) {
        int s4 = wr + mt * 16 + l4 * 4;
        u16x4 pk;
        pk.x = bf(acc[mt][nt][0] + bvv);
        pk.y = bf(acc[mt][nt][1] + bvv);
        pk.z = bf(acc[mt][nt][2] + bvv);
        pk.w = bf(acc[mt][nt][3] + bvv);
        *(u16x4*)(smem + dl * 128 + (s4 ^ ((dl & 7) << 3))) = pk;
      }
    }
    __syncthreads();
    const int bb = brow >> 10;
    const int seq0 = brow & 1023;
    const int chunk = tid & 15;
#pragma unroll
    for (int p = 0; p < 8; ++p) {
      int dl = p * 16 + (tid >> 4);
      bf16x8 v = *(const bf16x8*)(smem + dl * 128 + ((chunk * 8) ^ ((dl & 7) << 3)));
      *(bf16x8*)(vo + ((size_t)bb * 1024 + bcol + dl) * 1024 + seq0 + chunk * 8) = v;
    }
    return;
  }

  u16* outp = mode == 0 ? qo : ko;
  const float scale = mode == 0 ? (0.125f * LOG2E) : 1.0f;
#pragma unroll
  for (int nt = 0; nt < 4; ++nt) {
    int gc = bcol + wc + nt * 16 + l15;
    float bvv = bias[gc];
#pragma unroll
    for (int mt = 0; mt < 4; ++mt) {
#pragma unroll
      for (int i = 0; i < 4; ++i) {
        int gm = brow + wr + mt * 16 + l4 * 4 + i;
        outp[(size_t)gm * 1024 + gc] = bf((acc[mt][nt][i] + bvv) * scale);
      }
    }
  }
}

// ---------------- O-proj GEMM: f32 acc+bias+resid ----------------
__global__ __launch_bounds__(256) void k_gemm_o(const u16* __restrict__ A,
                                                const u16* __restrict__ WT,
                                                const float* __restrict__ bias,
                                                const float* __restrict__ resid,
                                                float* __restrict__ outp) {
  __shared__ __align__(16) u16 smem[2 * 128 * 64];
  u16* As = smem;
  u16* Bs = smem + 128 * 64;
  const int tid = threadIdx.x;
  const int lane = tid & 63;
  const int wave = tid >> 6;
  const int brow = blockIdx.y * 128;
  const int bcol = blockIdx.x * 128;
  const int wr = (wave >> 1) * 64;
  const int wc = (wave & 1) * 64;
  const int l15 = lane & 15, l4 = lane >> 4;

  f32x4 acc[4][4] = {};
  const int crow0 = tid >> 3;
  const int kpos = (tid & 7) * 8;

  for (int t = 0; t < 16; ++t) {
    const int k0 = t * 64;
#pragma unroll
    for (int r = 0; r < 4; ++r) {
      int crow = r * 32 + crow0;
      u16* ldsbase_a = As + ((r * 256 + wave * 64) << 3);
      u16* ldsbase_b = Bs + ((r * 256 + wave * 64) << 3);
      gload16(A + (size_t)(brow + crow) * 1024 + k0 + kpos, ldsbase_a);
      gload16(WT + (size_t)(bcol + crow) * 1024 + k0 + kpos, ldsbase_b);
    }
    __syncthreads();
#pragma unroll
    for (int kk = 0; kk < 2; ++kk) {
      bf16x8 af[4], bg[4];
      const int kb = kk * 32 + l4 * 8;
#pragma unroll
      for (int mt = 0; mt < 4; ++mt)
        af[mt] = *(const bf16x8*)(As + (wr + mt * 16 + l15) * 64 + kb);
#pragma unroll
      for (int nt = 0; nt < 4; ++nt)
        bg[nt] = *(const bf16x8*)(Bs + (wc + nt * 16 + l15) * 64 + kb);
#pragma unroll
      for (int mt = 0; mt < 4; ++mt)
#pragma unroll
        for (int nt = 0; nt < 4; ++nt)
          acc[mt][nt] = mfma16(af[mt], bg[nt], acc[mt][nt]);
    }
    __syncthreads();
  }

#pragma unroll
  for (int nt = 0; nt < 4; ++nt) {
    int gc = bcol + wc + nt * 16 + l15;
    float bvv = bias[gc];
#pragma unroll
    for (int mt = 0; mt < 4; ++mt) {
#pragma unroll
      for (int i = 0; i < 4; ++i) {
        int gm = brow + wr + mt * 16 + l4 * 4 + i;
        outp[(size_t)gm * 1024 + gc] =
            acc[mt][nt][i] + bvv + resid[(size_t)gm * 1024 + gc];
      }
    }
  }
}

// ---------------- attention v14: P3 V direct-to-register (no LDS staging) ----------------
// P1: DMA-staged K, wave-private counted vmcnt (unchanged).
// P2: softmax (unchanged).
// P3: per-lane 16B global loads of V (L1/L2-resident; each 128B line reused 8x);
//     compiler-scheduled, no waitcnt/barrier machinery (m169: staging L2-fit
//     data is pure overhead).
__global__ __launch_bounds__(256, 3) void k_attn(const u16* __restrict__ q,
                                                 const u16* __restrict__ kk_,
                                                 const u16* __restrict__ vt,
                                                 const u16* __restrict__ pbb,
                                                 float* __restrict__ attn_out,
                                                 u16* __restrict__ aout) {
  __shared__ __align__(16) u16 sc[16 * 1024];   // 32 KB scores/P, XOR-swizzled
  __shared__ __align__(16) u16 kst[4][2][1024]; // 16 KB: per-wave dbuf (P1 only)
  __shared__ float invbuf[16];
  const int tid = threadIdx.x;
  const int lane = tid & 63;
  const int wave = tid >> 6;        // 0..3
  const int bid = blockIdx.x;
  const int swz = (bid & 7) * 1024 + (bid >> 3);  // XCD-chunked (8192%8==0)
  const int bh = swz >> 6;          // 0..127
  const int q0 = (swz & 63) * 16;
  const int b = bh >> 4, h = bh & 15;
  const int l15 = lane & 15, l4 = lane >> 4;
  const int srow8 = (lane >> 3) & 7;
  const int sgsw = (lane & 7) ^ srow8;
  u16* const kw = &kst[wave][0][0];

  bf16x8 qf0, qf1;
  {
    const u16* qp = q + ((size_t)(b * 1024 + q0 + l15)) * 1024 + h * 64 + l4 * 8;
    qf0 = *(const bf16x8*)qp;
    qf1 = *(const bf16x8*)(qp + 32);
  }

  // ---- P1: S = K.Q^T -> sc; wave-private kv quarter, 16 chunks of 16 ----
  {
    const int kvb = wave * 256;
    const u16* kbase = kk_ + (size_t)(b * 1024 + kvb) * 1024 + h * 64 + sgsw * 8;
    gload16(kbase + (size_t)srow8 * 1024, kw);
    gload16(kbase + (size_t)(8 + srow8) * 1024, kw + 512);
    for (int c = 0; c < 16; ++c) {
      if (c < 15) {
        const u16* nsrc = kbase + (size_t)((c + 1) * 16 + srow8) * 1024;
        u16* ndst = kw + ((c + 1) & 1) * 1024;
        gload16(nsrc, ndst);
        gload16(nsrc + 8 * 1024, ndst + 512);
        asm volatile("s_waitcnt vmcnt(2)" ::: "memory");
      } else {
        asm volatile("s_waitcnt vmcnt(0)" ::: "memory");
      }
      __builtin_amdgcn_sched_barrier(0);
      const u16* kb = kw + (c & 1) * 1024;
      const int r = l15;
      bf16x8 k0 = *(const bf16x8*)(kb + r * 64 + ((l4 ^ (r & 7)) << 3));
      bf16x8 k1 = *(const bf16x8*)(kb + r * 64 + (((4 + l4) ^ (r & 7)) << 3));
      f32x4 cc = {};
      cc = mfma16(k0, qf0, cc);
      cc = mfma16(k1, qf1, cc);
      const int c4 = kvb + c * 16 + l4 * 4;
      u16x4 pk;
      pk.x = bf(cc[0]); pk.y = bf(cc[1]); pk.z = bf(cc[2]); pk.w = bf(cc[3]);
      *(u16x4*)(sc + l15 * 1024 + (c4 ^ ((l15 & 7) << 3))) = pk;
    }
  }
  __syncthreads();   // sc complete (per-wave DMAs already drained)

  // ---- P2: softmax + pbb add ----
  const int r2 = tid >> 4;
  const int l2 = tid & 15;
  {
    const int rx = (r2 & 7) << 3;
    u16* rowp = sc + r2 * 1024;
    const u16* pbrow = pbb + (size_t)(q0 + r2) * 1024 + l2 * 8;
    bf16x8 R[8];
#pragma unroll
    for (int g = 0; g < 8; ++g) {
      bf16x8 v = *(const bf16x8*)(rowp + ((g * 128 + l2 * 8) ^ rx));
      bf16x8 pv = *(const bf16x8*)(pbrow + g * 128);
      bf16x8 s;
#pragma unroll
      for (int j = 0; j < 8; ++j) s[j] = (short)bf(b2f(v[j]) + b2f(pv[j]));
      R[g] = s;
    }
    float mx = -3e38f;
#pragma unroll
    for (int g = 0; g < 8; ++g)
#pragma unroll
      for (int j = 0; j < 8; ++j) mx = fmaxf(mx, b2f(R[g][j]));
#pragma unroll
    for (int o = 1; o < 16; o <<= 1) mx = fmaxf(mx, __shfl_xor(mx, o));
    float sum = 0.f;
#pragma unroll
    for (int g = 0; g < 8; ++g) {
      bf16x8 e;
#pragma unroll
      for (int j = 0; j < 8; ++j) {
        float t = exp2f(b2f(R[g][j]) - mx);
        sum += t;
        e[j] = (short)bf(t);
      }
      *(bf16x8*)(rowp + ((g * 128 + l2 * 8) ^ rx)) = e;  // unnormalized exp
    }
#pragma unroll
    for (int o = 1; o < 16; o <<= 1) sum += __shfl_xor(sum, o);
    if (l2 == 0) invbuf[r2] = 1.f / sum;
  }
  __syncthreads();   // exp-P + invbuf visible

  // ---- P3: O = P.V^T; V loaded per-lane direct to registers ----
  f32x4 oacc = {};
  {
    // lane's V row = wave*16 + l15 (B-frag row = lane&15); cols walk c/ks.
    const u16* vrow = vt + (size_t)(b * 1024 + h * 64 + wave * 16 + l15) * 1024 + l4 * 8;
    const u16* prow = sc + l15 * 1024;
    const int prx = (l15 & 7) << 3;
#pragma unroll 4
    for (int c = 0; c < 16; ++c) {
#pragma unroll
      for (int ks = 0; ks < 2; ++ks) {
        const int e = c * 64 + ks * 32;
        bf16x8 vf = *(const bf16x8*)(vrow + e);
        bf16x8 pf = *(const bf16x8*)(prow + ((e + l4 * 8) ^ prx));
        oacc = mfma16(pf, vf, oacc);
      }
    }
  }

  // ---- tail: all global stores ----
#pragma unroll
  for (int i = 0; i < 4; ++i) {
    float iv = invbuf[l4 * 4 + i];
    aout[(size_t)(b * 1024 + q0 + l4 * 4 + i) * 1024 + h * 64 + wave * 16 + l15] =
        bf(oacc[i] * iv);
  }
  // attn_out: NT full-line stores (v10 A/B: plain = +94us L2 thrash)
#pragma unroll
  for (int it = 0; it < 16; ++it) {
    const int ebase = (tid * 4) ^ ((it & 7) << 3);
    u16x4 p = *(const u16x4*)(sc + it * 1024 + ebase);
    const float iv = invbuf[it];
    f32x4 w;
    w[0] = b2f((short)p.x) * iv;
    w[1] = b2f((short)p.y) * iv;
    w[2] = b2f((short)p.z) * iv;
    w[3] = b2f((short)p.w) * iv;
    __builtin_nontemporal_store(
        w, (f32x4*)(attn_out + ((size_t)bh * 1024 + q0 + it) * 1024 + tid * 4));
  }
}

// ---------------- LayerNorm: one wave per row ----------------
__global__ __launch_bounds__(256) void k_ln(const float* __restrict__ y,
                                            const float* __restrict__ g,
                                            const float* __restrict__ be,
                                            float* __restrict__ o) {
  const int lane = threadIdx.x & 63;
  const int wave = threadIdx.x >> 6;
  size_t row = (size_t)blockIdx.x * 4 + wave;
  const float* yr = y + row * 1024;
  float4 v[4];
  float s = 0.f, sq = 0.f;
#pragma unroll
  for (int i = 0; i < 4; ++i) {
    v[i] = *(const float4*)(yr + i * 256 + lane * 4);
    s += v[i].x + v[i].y + v[i].z + v[i].w;
    sq += v[i].x * v[i].x + v[i].y * v[i].y + v[i].z * v[i].z + v[i].w * v[i].w;
  }
#pragma unroll
  for (int off = 1; off < 64; off <<= 1) {
    s += __shfl_xor(s, off);
    sq += __shfl_xor(sq, off);
  }
  float mu = s * (1.f / 1024.f);
  float var = sq * (1.f / 1024.f) - mu * mu;
  float rs = rsqrtf(fmaxf(var, 0.f) + 1e-5f);
  float* orow = o + row * 1024;
#pragma unroll
  for (int i = 0; i < 4; ++i) {
    int c = i * 256 + lane * 4;
    float4 gg = *(const float4*)(g + c);
    float4 bb = *(const float4*)(be + c);
    float4 rr;
    rr.x = (v[i].x - mu) * rs * gg.x + bb.x;
    rr.y = (v[i].y - mu) * rs * gg.y + bb.y;
    rr.z = (v[i].z - mu) * rs * gg.z + bb.z;
    rr.w = (v[i].w - mu) * rs * gg.w + bb.w;
    *(float4*)(orow + c) = rr;
  }
}

extern "C" void kernel_launch(void* const* d_in, const int* in_sizes, int n_in,
                              void* d_out, int out_size, void* d_ws, size_t ws_size,
                              hipStream_t stream) {
  const float* x = (const float*)d_in[0];
  const float* Wq = (const float*)d_in[1];
  const float* bq = (const float*)d_in[2];
  const float* Wk = (const float*)d_in[3];
  const float* bk = (const float*)d_in[4];
  const float* Wv = (const float*)d_in[5];
  const float* bv = (const float*)d_in[6];
  const float* pb = (const float*)d_in[7];
  const float* Wo = (const float*)d_in[8];
  const float* bo = (const float*)d_in[9];
  const float* gamma = (const float*)d_in[10];
  const float* beta = (const float*)d_in[11];

  char* ws = (char*)d_ws;
  u16* xb = (u16*)(ws);
  u16* aows = (u16*)(ws);
  u16* wqT = (u16*)(ws + (16u << 20));
  u16* wkT = (u16*)(ws + (18u << 20));
  u16* wvT = (u16*)(ws + (20u << 20));
  u16* woT = (u16*)(ws + (22u << 20));
  u16* qws = (u16*)(ws + (24u << 20));
  u16* kws = (u16*)(ws + (40u << 20));
  u16* vtws = (u16*)(ws + (56u << 20));
  float* yws = (float*)(ws + (72u << 20));
  u16* pbb = (u16*)(ws + (72u << 20));  // overlays yws head; dead before gemm_o writes

  float* out_ln = (float*)d_out;
  float* out_attn = out_ln + (size_t)Mm * Dd;

  k_prep<<<13312, 256, 0, stream>>>(x, xb, pb, pbb, Wq, Wk, Wv, Wo,
                                    wqT, wkT, wvT, woT);
  k_gemm_qkv<<<dim3(8, 64, 3), 256, 0, stream>>>(xb, wqT, wkT, wvT,
                                                 bq, bk, bv, qws, kws, vtws);
  k_attn<<<8192, 256, 0, stream>>>(qws, kws, vtws, pbb, out_attn, aows);
  k_gemm_o<<<dim3(8, 64), 256, 0, stream>>>(aows, woT, bo, x, yws);
  k_ln<<<2048, 256, 0, stream>>>(yws, gamma, beta, out_ln);
}

// Round 15
// 305.581 us; speedup vs baseline: 1.1361x; 1.1361x over previous
//
#include <hip/hip_runtime.h>
#include <hip/hip_bf16.h>
#include <stdint.h>
#include <stddef.h>

#define DI __device__ __forceinline__

typedef unsigned short u16;
typedef float f32x4 __attribute__((ext_vector_type(4)));
typedef short bf16x8 __attribute__((ext_vector_type(8)));
typedef u16 u16x4 __attribute__((ext_vector_type(4)));

constexpr int Mm = 8192;
constexpr int Dd = 1024;
constexpr float LOG2E = 1.44269504088896f;

DI u16 bf(float f) {
  __hip_bfloat16 h = __float2bfloat16(f);
  return *reinterpret_cast<u16*>(&h);
}

DI float b2f(short s) {
  union { float f; unsigned u; } v;
  v.u = ((unsigned)(unsigned short)s) << 16;
  return v.f;
}

DI f32x4 mfma16(bf16x8 a, bf16x8 b, f32x4 c) {
  return __builtin_amdgcn_mfma_f32_16x16x32_bf16(a, b, c, 0, 0, 0);
}

DI void gload16(const u16* g, u16* l) {
  __builtin_amdgcn_global_load_lds(
      (const __attribute__((address_space(1))) void*)(g),
      (__attribute__((address_space(3))) void*)(l), 16, 0, 0);
}

// ---------------- prep: cvt x | pb->bf16*log2e | transpose 4 W ----------------
__global__ __launch_bounds__(256) void k_prep(const float* __restrict__ x,
                                              u16* __restrict__ xb,
                                              const float* __restrict__ pb,
                                              u16* __restrict__ pbb,
                                              const float* __restrict__ W0,
                                              const float* __restrict__ W1,
                                              const float* __restrict__ W2,
                                              const float* __restrict__ W3,
                                              u16* __restrict__ T0,
                                              u16* __restrict__ T1,
                                              u16* __restrict__ T2,
                                              u16* __restrict__ T3) {
  __shared__ float t[32][33];
  const int bid = blockIdx.x;
  const int tid = threadIdx.x;
  if (bid < 8192) {
    size_t i = (size_t)bid * 256 + tid;
    float4 v = *(const float4*)(x + i * 4);
    u16x4 r;
    r.x = bf(v.x); r.y = bf(v.y); r.z = bf(v.z); r.w = bf(v.w);
    *(u16x4*)(xb + i * 4) = r;
  } else if (bid < 9216) {
    size_t i = (size_t)(bid - 8192) * 256 + tid;
    float4 v = *(const float4*)(pb + i * 4);
    u16x4 r;
    r.x = bf(v.x * LOG2E); r.y = bf(v.y * LOG2E);
    r.z = bf(v.z * LOG2E); r.w = bf(v.w * LOG2E);
    *(u16x4*)(pbb + i * 4) = r;
  } else {
    const int tt = bid - 9216;
    const int z = tt >> 10;
    const int rem = tt & 1023;
    const float* W;
    u16* T;
    switch (z) {
      case 0: W = W0; T = T0; break;
      case 1: W = W1; T = T1; break;
      case 2: W = W2; T = T2; break;
      default: W = W3; T = T3; break;
    }
    const int bx = (rem & 31) * 32;
    const int by = (rem >> 5) * 32;
    const int tx = tid & 31, ty = tid >> 5;
#pragma unroll
    for (int i = 0; i < 4; ++i)
      t[ty + i * 8][tx] = W[(size_t)(bx + ty + i * 8) * 1024 + by + tx];
    __syncthreads();
#pragma unroll
    for (int i = 0; i < 4; ++i)
      T[(size_t)(by + ty + i * 8) * 1024 + bx + tx] = bf(t[tx][ty + i * 8]);
  }
}

// ---------------- QKV mega-GEMM, XCD-chunked 1-D grid (1536 blocks) ----------------
// wgid = (bid&7)*192 + (bid>>3): each XCD owns contiguous brow-panels -> A-panel
// reuse hits its local L2 (T1). mode = wgid>>9, brow = ((wgid&511)>>3)*128,
// bcol = (wgid&7)*128.
__global__ __launch_bounds__(256) void k_gemm_qkv(const u16* __restrict__ A,
                                                  const u16* __restrict__ wqT,
                                                  const u16* __restrict__ wkT,
                                                  const u16* __restrict__ wvT,
                                                  const float* __restrict__ bq,
                                                  const float* __restrict__ bk,
                                                  const float* __restrict__ bv,
                                                  u16* __restrict__ qo,
                                                  u16* __restrict__ ko,
                                                  u16* __restrict__ vo) {
  __shared__ __align__(16) u16 smem[2 * 128 * 64];
  u16* As = smem;
  u16* Bs = smem + 128 * 64;
  const int bid = blockIdx.x;
  const int wgid = (bid & 7) * 192 + (bid >> 3);
  const int mode = wgid >> 9;
  const int rem = wgid & 511;
  const int brow = (rem >> 3) * 128;
  const int bcol = (rem & 7) * 128;
  const u16* WT = mode == 0 ? wqT : (mode == 1 ? wkT : wvT);
  const float* bias = mode == 0 ? bq : (mode == 1 ? bk : bv);
  const int tid = threadIdx.x;
  const int lane = tid & 63;
  const int wave = tid >> 6;
  const int wr = (wave >> 1) * 64;
  const int wc = (wave & 1) * 64;
  const int l15 = lane & 15, l4 = lane >> 4;

  f32x4 acc[4][4] = {};
  const int crow0 = tid >> 3;
  const int kpos = (tid & 7) * 8;

  for (int t = 0; t < 16; ++t) {
    const int k0 = t * 64;
#pragma unroll
    for (int r = 0; r < 4; ++r) {
      int crow = r * 32 + crow0;
      u16* ldsbase_a = As + ((r * 256 + wave * 64) << 3);
      u16* ldsbase_b = Bs + ((r * 256 + wave * 64) << 3);
      gload16(A + (size_t)(brow + crow) * 1024 + k0 + kpos, ldsbase_a);
      gload16(WT + (size_t)(bcol + crow) * 1024 + k0 + kpos, ldsbase_b);
    }
    __syncthreads();
#pragma unroll
    for (int kk = 0; kk < 2; ++kk) {
      bf16x8 af[4], bg[4];
      const int kb = kk * 32 + l4 * 8;
#pragma unroll
      for (int mt = 0; mt < 4; ++mt)
        af[mt] = *(const bf16x8*)(As + (wr + mt * 16 + l15) * 64 + kb);
#pragma unroll
      for (int nt = 0; nt < 4; ++nt)
        bg[nt] = *(const bf16x8*)(Bs + (wc + nt * 16 + l15) * 64 + kb);
#pragma unroll
      for (int mt = 0; mt < 4; ++mt)
#pragma unroll
        for (int nt = 0; nt < 4; ++nt)
          acc[mt][nt] = mfma16(af[mt], bg[nt], acc[mt][nt]);
    }
    __syncthreads();
  }

  if (mode == 2) {
#pragma unroll
    for (int nt = 0; nt < 4; ++nt) {
      int dl = wc + nt * 16 + l15;
      float bvv = bias[bcol + dl];
#pragma unroll
      for (int mt = 0; mt < 4; ++mt) {
        int s4 = wr + mt * 16 + l4 * 4;
        u16x4 pk;
        pk.x = bf(acc[mt][nt][0] + bvv);
        pk.y = bf(acc[mt][nt][1] + bvv);
        pk.z = bf(acc[mt][nt][2] + bvv);
        pk.w = bf(acc[mt][nt][3] + bvv);
        *(u16x4*)(smem + dl * 128 + (s4 ^ ((dl & 7) << 3))) = pk;
      }
    }
    __syncthreads();
    const int bb = brow >> 10;
    const int seq0 = brow & 1023;
    const int chunk = tid & 15;
#pragma unroll
    for (int p = 0; p < 8; ++p) {
      int dl = p * 16 + (tid >> 4);
      bf16x8 v = *(const bf16x8*)(smem + dl * 128 + ((chunk * 8) ^ ((dl & 7) << 3)));
      *(bf16x8*)(vo + ((size_t)bb * 1024 + bcol + dl) * 1024 + seq0 + chunk * 8) = v;
    }
    return;
  }

  u16* outp = mode == 0 ? qo : ko;
  const float scale = mode == 0 ? (0.125f * LOG2E) : 1.0f;
#pragma unroll
  for (int nt = 0; nt < 4; ++nt) {
    int gc = bcol + wc + nt * 16 + l15;
    float bvv = bias[gc];
#pragma unroll
    for (int mt = 0; mt < 4; ++mt) {
#pragma unroll
      for (int i = 0; i < 4; ++i) {
        int gm = brow + wr + mt * 16 + l4 * 4 + i;
        outp[(size_t)gm * 1024 + gc] = bf((acc[mt][nt][i] + bvv) * scale);
      }
    }
  }
}

// ---------------- O-proj GEMM, XCD-chunked 1-D grid (512 blocks) ----------------
__global__ __launch_bounds__(256) void k_gemm_o(const u16* __restrict__ A,
                                                const u16* __restrict__ WT,
                                                const float* __restrict__ bias,
                                                const float* __restrict__ resid,
                                                float* __restrict__ outp) {
  __shared__ __align__(16) u16 smem[2 * 128 * 64];
  u16* As = smem;
  u16* Bs = smem + 128 * 64;
  const int bid = blockIdx.x;
  const int wgid = (bid & 7) * 64 + (bid >> 3);
  const int brow = (wgid >> 3) * 128;
  const int bcol = (wgid & 7) * 128;
  const int tid = threadIdx.x;
  const int lane = tid & 63;
  const int wave = tid >> 6;
  const int wr = (wave >> 1) * 64;
  const int wc = (wave & 1) * 64;
  const int l15 = lane & 15, l4 = lane >> 4;

  f32x4 acc[4][4] = {};
  const int crow0 = tid >> 3;
  const int kpos = (tid & 7) * 8;

  for (int t = 0; t < 16; ++t) {
    const int k0 = t * 64;
#pragma unroll
    for (int r = 0; r < 4; ++r) {
      int crow = r * 32 + crow0;
      u16* ldsbase_a = As + ((r * 256 + wave * 64) << 3);
      u16* ldsbase_b = Bs + ((r * 256 + wave * 64) << 3);
      gload16(A + (size_t)(brow + crow) * 1024 + k0 + kpos, ldsbase_a);
      gload16(WT + (size_t)(bcol + crow) * 1024 + k0 + kpos, ldsbase_b);
    }
    __syncthreads();
#pragma unroll
    for (int kk = 0; kk < 2; ++kk) {
      bf16x8 af[4], bg[4];
      const int kb = kk * 32 + l4 * 8;
#pragma unroll
      for (int mt = 0; mt < 4; ++mt)
        af[mt] = *(const bf16x8*)(As + (wr + mt * 16 + l15) * 64 + kb);
#pragma unroll
      for (int nt = 0; nt < 4; ++nt)
        bg[nt] = *(const bf16x8*)(Bs + (wc + nt * 16 + l15) * 64 + kb);
#pragma unroll
      for (int mt = 0; mt < 4; ++mt)
#pragma unroll
        for (int nt = 0; nt < 4; ++nt)
          acc[mt][nt] = mfma16(af[mt], bg[nt], acc[mt][nt]);
    }
    __syncthreads();
  }

#pragma unroll
  for (int nt = 0; nt < 4; ++nt) {
    int gc = bcol + wc + nt * 16 + l15;
    float bvv = bias[gc];
#pragma unroll
    for (int mt = 0; mt < 4; ++mt) {
#pragma unroll
      for (int i = 0; i < 4; ++i) {
        int gm = brow + wr + mt * 16 + l4 * 4 + i;
        outp[(size_t)gm * 1024 + gc] =
            acc[mt][nt][i] + bvv + resid[(size_t)gm * 1024 + gc];
      }
    }
  }
}

// ---------------- attention v13 (best known: 310us): wave-specialized ----------------
__global__ __launch_bounds__(256, 3) void k_attn(const u16* __restrict__ q,
                                                 const u16* __restrict__ kk_,
                                                 const u16* __restrict__ vt,
                                                 const u16* __restrict__ pbb,
                                                 float* __restrict__ attn_out,
                                                 u16* __restrict__ aout) {
  __shared__ __align__(16) u16 sc[16 * 1024];   // 32 KB scores/P, XOR-swizzled
  __shared__ __align__(16) u16 kst[8192];       // 16 KB stage (repartitioned per phase)
  __shared__ float invbuf[16];
  const int tid = threadIdx.x;
  const int lane = tid & 63;
  const int wave = tid >> 6;        // 0..3
  const int bid = blockIdx.x;
  const int swz = (bid & 7) * 1024 + (bid >> 3);  // XCD-chunked (8192%8==0)
  const int bh = swz >> 6;          // 0..127
  const int q0 = (swz & 63) * 16;
  const int b = bh >> 4, h = bh & 15;
  const int l15 = lane & 15, l4 = lane >> 4;
  const int srow8 = (lane >> 3) & 7;
  const int sgsw = (lane & 7) ^ srow8;

  bf16x8 qf0, qf1;
  {
    const u16* qp = q + ((size_t)(b * 1024 + q0 + l15)) * 1024 + h * 64 + l4 * 8;
    qf0 = *(const bf16x8*)qp;
    qf1 = *(const bf16x8*)(qp + 32);
  }

  // ---- P1: S = K.Q^T -> sc; wave-private kv quarter, 16 chunks of 16 ----
  {
    u16* const kw = kst + wave * 2048;  // 2 x 1024 u16 dbuf
    const int kvb = wave * 256;
    const u16* kbase = kk_ + (size_t)(b * 1024 + kvb) * 1024 + h * 64 + sgsw * 8;
    gload16(kbase + (size_t)srow8 * 1024, kw);
    gload16(kbase + (size_t)(8 + srow8) * 1024, kw + 512);
    for (int c = 0; c < 16; ++c) {
      if (c < 15) {
        const u16* nsrc = kbase + (size_t)((c + 1) * 16 + srow8) * 1024;
        u16* ndst = kw + ((c + 1) & 1) * 1024;
        gload16(nsrc, ndst);
        gload16(nsrc + 8 * 1024, ndst + 512);
        asm volatile("s_waitcnt vmcnt(2)" ::: "memory");
      } else {
        asm volatile("s_waitcnt vmcnt(0)" ::: "memory");
      }
      __builtin_amdgcn_sched_barrier(0);
      const u16* kb = kw + (c & 1) * 1024;
      const int r = l15;
      bf16x8 k0 = *(const bf16x8*)(kb + r * 64 + ((l4 ^ (r & 7)) << 3));
      bf16x8 k1 = *(const bf16x8*)(kb + r * 64 + (((4 + l4) ^ (r & 7)) << 3));
      f32x4 cc = {};
      cc = mfma16(k0, qf0, cc);
      cc = mfma16(k1, qf1, cc);
      const int c4 = kvb + c * 16 + l4 * 4;
      u16x4 pk;
      pk.x = bf(cc[0]); pk.y = bf(cc[1]); pk.z = bf(cc[2]); pk.w = bf(cc[3]);
      *(u16x4*)(sc + l15 * 1024 + (c4 ^ ((l15 & 7) << 3))) = pk;
    }
  }
  __syncthreads();   // sc complete; kst dead (P1 layout)

  // PV waves (0-1) prefetch their V chunk 0 (4 x 1KB) -> lands during softmax.
  const u16* vbase2 = vt + (size_t)(b * 1024 + h * 64 + wave * 32 + srow8) * 1024 + sgsw * 8;
  u16* const kw3 = kst + wave * 4096;  // 2 x 2048 u16 dbuf (waves 0-1 only)
  if (wave < 2) {
#pragma unroll
    for (int i = 0; i < 4; ++i)
      gload16(vbase2 + (size_t)(i * 8) * 1024, kw3 + i * 512);
  }

  // ---- P2: softmax + pbb add (all waves) ----
  const int r2 = tid >> 4;
  const int l2 = tid & 15;
  {
    const int rx = (r2 & 7) << 3;
    u16* rowp = sc + r2 * 1024;
    const u16* pbrow = pbb + (size_t)(q0 + r2) * 1024 + l2 * 8;
    bf16x8 R[8];
#pragma unroll
    for (int g = 0; g < 8; ++g) {
      bf16x8 v = *(const bf16x8*)(rowp + ((g * 128 + l2 * 8) ^ rx));
      bf16x8 pv = *(const bf16x8*)(pbrow + g * 128);
      bf16x8 s;
#pragma unroll
      for (int j = 0; j < 8; ++j) s[j] = (short)bf(b2f(v[j]) + b2f(pv[j]));
      R[g] = s;
    }
    float mx = -3e38f;
#pragma unroll
    for (int g = 0; g < 8; ++g)
#pragma unroll
      for (int j = 0; j < 8; ++j) mx = fmaxf(mx, b2f(R[g][j]));
#pragma unroll
    for (int o = 1; o < 16; o <<= 1) mx = fmaxf(mx, __shfl_xor(mx, o));
    float sum = 0.f;
#pragma unroll
    for (int g = 0; g < 8; ++g) {
      bf16x8 e;
#pragma unroll
      for (int j = 0; j < 8; ++j) {
        float t = exp2f(b2f(R[g][j]) - mx);
        sum += t;
        e[j] = (short)bf(t);
      }
      *(bf16x8*)(rowp + ((g * 128 + l2 * 8) ^ rx)) = e;  // unnormalized exp
    }
#pragma unroll
    for (int o = 1; o < 16; o <<= 1) sum += __shfl_xor(sum, o);
    if (l2 == 0) invbuf[r2] = 1.f / sum;
  }
  __syncthreads();   // exp-P + invbuf visible; PV waves' V0 drained

  if (wave < 2) {
    // ---- PV waves: O = P.V^T over 32 d-rows, 16 chunks of 64 kv ----
    f32x4 oacc[2] = {};
    for (int c = 0; c < 16; ++c) {
      if (c < 15) {
        const u16* nsrc = vbase2 + (c + 1) * 64;
        u16* ndst = kw3 + ((c + 1) & 1) * 2048;
#pragma unroll
        for (int i = 0; i < 4; ++i)
          gload16(nsrc + (size_t)(i * 8) * 1024, ndst + i * 512);
        asm volatile("s_waitcnt vmcnt(4)" ::: "memory");
      } else {
        asm volatile("s_waitcnt vmcnt(0)" ::: "memory");
      }
      __builtin_amdgcn_sched_barrier(0);
      const u16* vb = kw3 + (c & 1) * 2048;
#pragma unroll
      for (int ks = 0; ks < 2; ++ks) {
        const int gg = ks * 4 + l4;
        const int e = c * 64 + ks * 32 + l4 * 8;
        bf16x8 pf = *(const bf16x8*)(sc + l15 * 1024 + (e ^ ((l15 & 7) << 3)));
#pragma unroll
        for (int dg = 0; dg < 2; ++dg) {
          const int vr = dg * 16 + l15;
          bf16x8 vf = *(const bf16x8*)(vb + vr * 64 + ((gg ^ (vr & 7)) << 3));
          oacc[dg] = mfma16(pf, vf, oacc[dg]);
        }
      }
    }
#pragma unroll
    for (int dg = 0; dg < 2; ++dg)
#pragma unroll
      for (int i = 0; i < 4; ++i) {
        float iv = invbuf[l4 * 4 + i];
        aout[(size_t)(b * 1024 + q0 + l4 * 4 + i) * 1024 + h * 64 + wave * 32 +
             dg * 16 + l15] = bf(oacc[dg][i] * iv);
      }
  } else {
    // ---- store waves: attn_out NT full-line stores (overlaps PV) ----
    const int tid2 = tid - 128;  // 0..127
#pragma unroll
    for (int it = 0; it < 32; ++it) {
      const int row = it >> 1;
      const int col4 = (it & 1) * 128 + tid2;
      const int ebase = (col4 * 4) ^ ((row & 7) << 3);
      u16x4 p = *(const u16x4*)(sc + row * 1024 + ebase);
      const float iv = invbuf[row];
      f32x4 w;
      w[0] = b2f((short)p.x) * iv;
      w[1] = b2f((short)p.y) * iv;
      w[2] = b2f((short)p.z) * iv;
      w[3] = b2f((short)p.w) * iv;
      __builtin_nontemporal_store(
          w, (f32x4*)(attn_out + ((size_t)bh * 1024 + q0 + row) * 1024 + col4 * 4));
    }
  }
}

// ---------------- LayerNorm: one wave per row ----------------
__global__ __launch_bounds__(256) void k_ln(const float* __restrict__ y,
                                            const float* __restrict__ g,
                                            const float* __restrict__ be,
                                            float* __restrict__ o) {
  const int lane = threadIdx.x & 63;
  const int wave = threadIdx.x >> 6;
  size_t row = (size_t)blockIdx.x * 4 + wave;
  const float* yr = y + row * 1024;
  float4 v[4];
  float s = 0.f, sq = 0.f;
#pragma unroll
  for (int i = 0; i < 4; ++i) {
    v[i] = *(const float4*)(yr + i * 256 + lane * 4);
    s += v[i].x + v[i].y + v[i].z + v[i].w;
    sq += v[i].x * v[i].x + v[i].y * v[i].y + v[i].z * v[i].z + v[i].w * v[i].w;
  }
#pragma unroll
  for (int off = 1; off < 64; off <<= 1) {
    s += __shfl_xor(s, off);
    sq += __shfl_xor(sq, off);
  }
  float mu = s * (1.f / 1024.f);
  float var = sq * (1.f / 1024.f) - mu * mu;
  float rs = rsqrtf(fmaxf(var, 0.f) + 1e-5f);
  float* orow = o + row * 1024;
#pragma unroll
  for (int i = 0; i < 4; ++i) {
    int c = i * 256 + lane * 4;
    float4 gg = *(const float4*)(g + c);
    float4 bb = *(const float4*)(be + c);
    float4 rr;
    rr.x = (v[i].x - mu) * rs * gg.x + bb.x;
    rr.y = (v[i].y - mu) * rs * gg.y + bb.y;
    rr.z = (v[i].z - mu) * rs * gg.z + bb.z;
    rr.w = (v[i].w - mu) * rs * gg.w + bb.w;
    *(float4*)(orow + c) = rr;
  }
}

extern "C" void kernel_launch(void* const* d_in, const int* in_sizes, int n_in,
                              void* d_out, int out_size, void* d_ws, size_t ws_size,
                              hipStream_t stream) {
  const float* x = (const float*)d_in[0];
  const float* Wq = (const float*)d_in[1];
  const float* bq = (const float*)d_in[2];
  const float* Wk = (const float*)d_in[3];
  const float* bk = (const float*)d_in[4];
  const float* Wv = (const float*)d_in[5];
  const float* bv = (const float*)d_in[6];
  const float* pb = (const float*)d_in[7];
  const float* Wo = (const float*)d_in[8];
  const float* bo = (const float*)d_in[9];
  const float* gamma = (const float*)d_in[10];
  const float* beta = (const float*)d_in[11];

  char* ws = (char*)d_ws;
  u16* xb = (u16*)(ws);
  u16* aows = (u16*)(ws);
  u16* wqT = (u16*)(ws + (16u << 20));
  u16* wkT = (u16*)(ws + (18u << 20));
  u16* wvT = (u16*)(ws + (20u << 20));
  u16* woT = (u16*)(ws + (22u << 20));
  u16* qws = (u16*)(ws + (24u << 20));
  u16* kws = (u16*)(ws + (40u << 20));
  u16* vtws = (u16*)(ws + (56u << 20));
  float* yws = (float*)(ws + (72u << 20));
  u16* pbb = (u16*)(ws + (72u << 20));  // overlays yws head; dead before gemm_o writes

  float* out_ln = (float*)d_out;
  float* out_attn = out_ln + (size_t)Mm * Dd;

  k_prep<<<13312, 256, 0, stream>>>(x, xb, pb, pbb, Wq, Wk, Wv, Wo,
                                    wqT, wkT, wvT, woT);
  k_gemm_qkv<<<1536, 256, 0, stream>>>(xb, wqT, wkT, wvT,
                                       bq, bk, bv, qws, kws, vtws);
  k_attn<<<8192, 256, 0, stream>>>(qws, kws, vtws, pbb, out_attn, aows);
  k_gemm_o<<<512, 256, 0, stream>>>(aows, woT, bo, x, yws);
  k_ln<<<2048, 256, 0, stream>>>(yws, gamma, beta, out_ln);
}

// Round 16
// 300.336 us; speedup vs baseline: 1.1559x; 1.0175x over previous
//
#include <hip/hip_runtime.h>
#include <hip/hip_bf16.h>
#include <stdint.h>
#include <stddef.h>

#define DI __device__ __forceinline__

typedef unsigned short u16;
typedef float f32x4 __attribute__((ext_vector_type(4)));
typedef short bf16x8 __attribute__((ext_vector_type(8)));
typedef u16 u16x4 __attribute__((ext_vector_type(4)));

constexpr int Mm = 8192;
constexpr int Dd = 1024;
constexpr float LOG2E = 1.44269504088896f;

DI u16 bf(float f) {
  __hip_bfloat16 h = __float2bfloat16(f);
  return *reinterpret_cast<u16*>(&h);
}

DI float b2f(short s) {
  union { float f; unsigned u; } v;
  v.u = ((unsigned)(unsigned short)s) << 16;
  return v.f;
}

DI f32x4 mfma16(bf16x8 a, bf16x8 b, f32x4 c) {
  return __builtin_amdgcn_mfma_f32_16x16x32_bf16(a, b, c, 0, 0, 0);
}

DI void gload16(const u16* g, u16* l) {
  __builtin_amdgcn_global_load_lds(
      (const __attribute__((address_space(1))) void*)(g),
      (__attribute__((address_space(3))) void*)(l), 16, 0, 0);
}

// ---------------- prep: cvt x | pb->bf16*log2e | transpose 4 W ----------------
__global__ __launch_bounds__(256) void k_prep(const float* __restrict__ x,
                                              u16* __restrict__ xb,
                                              const float* __restrict__ pb,
                                              u16* __restrict__ pbb,
                                              const float* __restrict__ W0,
                                              const float* __restrict__ W1,
                                              const float* __restrict__ W2,
                                              const float* __restrict__ W3,
                                              u16* __restrict__ T0,
                                              u16* __restrict__ T1,
                                              u16* __restrict__ T2,
                                              u16* __restrict__ T3) {
  __shared__ float t[32][33];
  const int bid = blockIdx.x;
  const int tid = threadIdx.x;
  if (bid < 8192) {
    size_t i = (size_t)bid * 256 + tid;
    float4 v = *(const float4*)(x + i * 4);
    u16x4 r;
    r.x = bf(v.x); r.y = bf(v.y); r.z = bf(v.z); r.w = bf(v.w);
    *(u16x4*)(xb + i * 4) = r;
  } else if (bid < 9216) {
    size_t i = (size_t)(bid - 8192) * 256 + tid;
    float4 v = *(const float4*)(pb + i * 4);
    u16x4 r;
    r.x = bf(v.x * LOG2E); r.y = bf(v.y * LOG2E);
    r.z = bf(v.z * LOG2E); r.w = bf(v.w * LOG2E);
    *(u16x4*)(pbb + i * 4) = r;
  } else {
    const int tt = bid - 9216;
    const int z = tt >> 10;
    const int rem = tt & 1023;
    const float* W;
    u16* T;
    switch (z) {
      case 0: W = W0; T = T0; break;
      case 1: W = W1; T = T1; break;
      case 2: W = W2; T = T2; break;
      default: W = W3; T = T3; break;
    }
    const int bx = (rem & 31) * 32;
    const int by = (rem >> 5) * 32;
    const int tx = tid & 31, ty = tid >> 5;
#pragma unroll
    for (int i = 0; i < 4; ++i)
      t[ty + i * 8][tx] = W[(size_t)(bx + ty + i * 8) * 1024 + by + tx];
    __syncthreads();
#pragma unroll
    for (int i = 0; i < 4; ++i)
      T[(size_t)(by + ty + i * 8) * 1024 + bx + tx] = bf(t[tx][ty + i * 8]);
  }
}

// ---------------- QKV mega-GEMM: 2-phase pipelined K-loop (T3 minimum recipe) ----
// XCD-chunked 1-D grid (1536 blocks). LDS: 2 x 32KB double buffer.
// Per K-step: issue next-tile STAGE early -> compute cur -> vmcnt(0)+barrier.
// Epilogues: LDS-transposed -> contiguous 16B stores (no scalar u16 stores).
__global__ __launch_bounds__(256) void k_gemm_qkv(const u16* __restrict__ A,
                                                  const u16* __restrict__ wqT,
                                                  const u16* __restrict__ wkT,
                                                  const u16* __restrict__ wvT,
                                                  const float* __restrict__ bq,
                                                  const float* __restrict__ bk,
                                                  const float* __restrict__ bv,
                                                  u16* __restrict__ qo,
                                                  u16* __restrict__ ko,
                                                  u16* __restrict__ vo) {
  __shared__ __align__(16) u16 smem[2][16384];  // [buf][A 8192 | B 8192] = 64 KB
  const int bid = blockIdx.x;
  const int wgid = (bid & 7) * 192 + (bid >> 3);
  const int mode = wgid >> 9;
  const int rem = wgid & 511;
  const int brow = (rem >> 3) * 128;
  const int bcol = (rem & 7) * 128;
  const u16* WT = mode == 0 ? wqT : (mode == 1 ? wkT : wvT);
  const float* bias = mode == 0 ? bq : (mode == 1 ? bk : bv);
  const int tid = threadIdx.x;
  const int lane = tid & 63;
  const int wave = tid >> 6;
  const int wr = (wave >> 1) * 64;
  const int wc = (wave & 1) * 64;
  const int l15 = lane & 15, l4 = lane >> 4;

  f32x4 acc[4][4] = {};
  const int crow0 = tid >> 3;
  const int kpos = (tid & 7) * 8;

  // prologue: stage tile 0, drain, barrier
#pragma unroll
  for (int r = 0; r < 4; ++r) {
    int crow = r * 32 + crow0;
    gload16(A + (size_t)(brow + crow) * 1024 + kpos,
            &smem[0][0] + ((r * 256 + wave * 64) << 3));
    gload16(WT + (size_t)(bcol + crow) * 1024 + kpos,
            &smem[0][0] + 8192 + ((r * 256 + wave * 64) << 3));
  }
  asm volatile("s_waitcnt vmcnt(0)" ::: "memory");
  __builtin_amdgcn_s_barrier();

  for (int t = 0; t < 16; ++t) {
    const int cur = t & 1;
    if (t < 15) {
      const int k0 = (t + 1) * 64;
#pragma unroll
      for (int r = 0; r < 4; ++r) {
        int crow = r * 32 + crow0;
        gload16(A + (size_t)(brow + crow) * 1024 + k0 + kpos,
                &smem[cur ^ 1][0] + ((r * 256 + wave * 64) << 3));
        gload16(WT + (size_t)(bcol + crow) * 1024 + k0 + kpos,
                &smem[cur ^ 1][0] + 8192 + ((r * 256 + wave * 64) << 3));
      }
      __builtin_amdgcn_sched_barrier(0);  // pin STAGE before compute
    }
    const u16* As = &smem[cur][0];
    const u16* Bs = As + 8192;
#pragma unroll
    for (int kk = 0; kk < 2; ++kk) {
      bf16x8 af[4], bg[4];
      const int kb = kk * 32 + l4 * 8;
#pragma unroll
      for (int mt = 0; mt < 4; ++mt)
        af[mt] = *(const bf16x8*)(As + (wr + mt * 16 + l15) * 64 + kb);
#pragma unroll
      for (int nt = 0; nt < 4; ++nt)
        bg[nt] = *(const bf16x8*)(Bs + (wc + nt * 16 + l15) * 64 + kb);
#pragma unroll
      for (int mt = 0; mt < 4; ++mt)
#pragma unroll
        for (int nt = 0; nt < 4; ++nt)
          acc[mt][nt] = mfma16(af[mt], bg[nt], acc[mt][nt]);
    }
    if (t < 15) {
      asm volatile("s_waitcnt vmcnt(0)" ::: "memory");  // next tile landed
      __builtin_amdgcn_sched_barrier(0);
      __builtin_amdgcn_s_barrier();                     // all waves: cur reads done
      __builtin_amdgcn_sched_barrier(0);
    }
  }
  __syncthreads();  // drain before smem reuse in epilogue

  u16* tile = &smem[0][0];  // 32 KB transpose tile

  if (mode == 2) {
    // V: transpose to [d_local][seq_local], store vo[b][d][seq]
#pragma unroll
    for (int nt = 0; nt < 4; ++nt) {
      int dl = wc + nt * 16 + l15;
      float bvv = bias[bcol + dl];
#pragma unroll
      for (int mt = 0; mt < 4; ++mt) {
        int s4 = wr + mt * 16 + l4 * 4;
        u16x4 pk;
        pk.x = bf(acc[mt][nt][0] + bvv);
        pk.y = bf(acc[mt][nt][1] + bvv);
        pk.z = bf(acc[mt][nt][2] + bvv);
        pk.w = bf(acc[mt][nt][3] + bvv);
        *(u16x4*)(tile + dl * 128 + (s4 ^ ((dl & 7) << 3))) = pk;
      }
    }
    __syncthreads();
    const int bb = brow >> 10;
    const int seq0 = brow & 1023;
    const int chunk = tid & 15;
#pragma unroll
    for (int p = 0; p < 8; ++p) {
      int dl = p * 16 + (tid >> 4);
      bf16x8 v = *(const bf16x8*)(tile + dl * 128 + ((chunk * 8) ^ ((dl & 7) << 3)));
      *(bf16x8*)(vo + ((size_t)bb * 1024 + bcol + dl) * 1024 + seq0 + chunk * 8) = v;
    }
    return;
  }

  // Q/K: row-major via LDS -> contiguous bf16x8 stores
  const float scale = mode == 0 ? (0.125f * LOG2E) : 1.0f;
#pragma unroll
  for (int nt = 0; nt < 4; ++nt) {
    int cl = wc + nt * 16 + l15;
    float bvv = bias[bcol + cl];
#pragma unroll
    for (int mt = 0; mt < 4; ++mt) {
#pragma unroll
      for (int i = 0; i < 4; ++i) {
        int rw = wr + mt * 16 + l4 * 4 + i;
        tile[rw * 128 + (cl ^ ((rw & 7) << 3))] = bf((acc[mt][nt][i] + bvv) * scale);
      }
    }
  }
  __syncthreads();
  u16* outp = mode == 0 ? qo : ko;
#pragma unroll
  for (int p = 0; p < 8; ++p) {
    int rw = p * 16 + (tid >> 4);
    int c0 = (tid & 15) * 8;
    bf16x8 v = *(const bf16x8*)(tile + rw * 128 + (c0 ^ ((rw & 7) << 3)));
    *(bf16x8*)(outp + (size_t)(brow + rw) * 1024 + bcol + c0) = v;
  }
}

// ---------------- O-proj GEMM: 2-phase K-loop + LDS f32 epilogue ----------------
// (resid reads and y stores become coalesced f32x4)
__global__ __launch_bounds__(256) void k_gemm_o(const u16* __restrict__ A,
                                                const u16* __restrict__ WT,
                                                const float* __restrict__ bias,
                                                const float* __restrict__ resid,
                                                float* __restrict__ outp) {
  __shared__ __align__(16) u16 smem[2][16384];  // 64 KB
  const int bid = blockIdx.x;
  const int wgid = (bid & 7) * 64 + (bid >> 3);
  const int brow = (wgid >> 3) * 128;
  const int bcol = (wgid & 7) * 128;
  const int tid = threadIdx.x;
  const int lane = tid & 63;
  const int wave = tid >> 6;
  const int wr = (wave >> 1) * 64;
  const int wc = (wave & 1) * 64;
  const int l15 = lane & 15, l4 = lane >> 4;

  f32x4 acc[4][4] = {};
  const int crow0 = tid >> 3;
  const int kpos = (tid & 7) * 8;

#pragma unroll
  for (int r = 0; r < 4; ++r) {
    int crow = r * 32 + crow0;
    gload16(A + (size_t)(brow + crow) * 1024 + kpos,
            &smem[0][0] + ((r * 256 + wave * 64) << 3));
    gload16(WT + (size_t)(bcol + crow) * 1024 + kpos,
            &smem[0][0] + 8192 + ((r * 256 + wave * 64) << 3));
  }
  asm volatile("s_waitcnt vmcnt(0)" ::: "memory");
  __builtin_amdgcn_s_barrier();

  for (int t = 0; t < 16; ++t) {
    const int cur = t & 1;
    if (t < 15) {
      const int k0 = (t + 1) * 64;
#pragma unroll
      for (int r = 0; r < 4; ++r) {
        int crow = r * 32 + crow0;
        gload16(A + (size_t)(brow + crow) * 1024 + k0 + kpos,
                &smem[cur ^ 1][0] + ((r * 256 + wave * 64) << 3));
        gload16(WT + (size_t)(bcol + crow) * 1024 + k0 + kpos,
                &smem[cur ^ 1][0] + 8192 + ((r * 256 + wave * 64) << 3));
      }
      __builtin_amdgcn_sched_barrier(0);
    }
    const u16* As = &smem[cur][0];
    const u16* Bs = As + 8192;
#pragma unroll
    for (int kk = 0; kk < 2; ++kk) {
      bf16x8 af[4], bg[4];
      const int kb = kk * 32 + l4 * 8;
#pragma unroll
      for (int mt = 0; mt < 4; ++mt)
        af[mt] = *(const bf16x8*)(As + (wr + mt * 16 + l15) * 64 + kb);
#pragma unroll
      for (int nt = 0; nt < 4; ++nt)
        bg[nt] = *(const bf16x8*)(Bs + (wc + nt * 16 + l15) * 64 + kb);
#pragma unroll
      for (int mt = 0; mt < 4; ++mt)
#pragma unroll
        for (int nt = 0; nt < 4; ++nt)
          acc[mt][nt] = mfma16(af[mt], bg[nt], acc[mt][nt]);
    }
    if (t < 15) {
      asm volatile("s_waitcnt vmcnt(0)" ::: "memory");
      __builtin_amdgcn_sched_barrier(0);
      __builtin_amdgcn_s_barrier();
      __builtin_amdgcn_sched_barrier(0);
    }
  }
  __syncthreads();

  // epilogue: acc+bias -> f32 LDS tile (64KB) -> +resid (f32x4) -> y (f32x4)
  float* ftile = (float*)&smem[0][0];  // 128 x 128 f32
#pragma unroll
  for (int nt = 0; nt < 4; ++nt) {
    int cl = wc + nt * 16 + l15;
    float bvv = bias[bcol + cl];
#pragma unroll
    for (int mt = 0; mt < 4; ++mt)
#pragma unroll
      for (int i = 0; i < 4; ++i) {
        int rw = wr + mt * 16 + l4 * 4 + i;
        ftile[rw * 128 + (cl ^ ((rw & 7) << 3))] = acc[mt][nt][i] + bvv;
      }
  }
  __syncthreads();
#pragma unroll
  for (int it = 0; it < 16; ++it) {
    int idx = it * 256 + tid;
    int rw = idx >> 5;
    int c4 = idx & 31;
    f32x4 y = *(const f32x4*)(ftile + rw * 128 + ((c4 * 4) ^ ((rw & 7) << 3)));
    f32x4 rs = *(const f32x4*)(resid + (size_t)(brow + rw) * 1024 + bcol + c4 * 4);
    y[0] += rs[0]; y[1] += rs[1]; y[2] += rs[2]; y[3] += rs[3];
    *(f32x4*)(outp + (size_t)(brow + rw) * 1024 + bcol + c4 * 4) = y;
  }
}

// ---------------- attention v13 (best known): wave-specialized ----------------
__global__ __launch_bounds__(256, 3) void k_attn(const u16* __restrict__ q,
                                                 const u16* __restrict__ kk_,
                                                 const u16* __restrict__ vt,
                                                 const u16* __restrict__ pbb,
                                                 float* __restrict__ attn_out,
                                                 u16* __restrict__ aout) {
  __shared__ __align__(16) u16 sc[16 * 1024];   // 32 KB scores/P, XOR-swizzled
  __shared__ __align__(16) u16 kst[8192];       // 16 KB stage (repartitioned per phase)
  __shared__ float invbuf[16];
  const int tid = threadIdx.x;
  const int lane = tid & 63;
  const int wave = tid >> 6;        // 0..3
  const int bid = blockIdx.x;
  const int swz = (bid & 7) * 1024 + (bid >> 3);  // XCD-chunked (8192%8==0)
  const int bh = swz >> 6;          // 0..127
  const int q0 = (swz & 63) * 16;
  const int b = bh >> 4, h = bh & 15;
  const int l15 = lane & 15, l4 = lane >> 4;
  const int srow8 = (lane >> 3) & 7;
  const int sgsw = (lane & 7) ^ srow8;

  bf16x8 qf0, qf1;
  {
    const u16* qp = q + ((size_t)(b * 1024 + q0 + l15)) * 1024 + h * 64 + l4 * 8;
    qf0 = *(const bf16x8*)qp;
    qf1 = *(const bf16x8*)(qp + 32);
  }

  // ---- P1: S = K.Q^T -> sc; wave-private kv quarter, 16 chunks of 16 ----
  {
    u16* const kw = kst + wave * 2048;  // 2 x 1024 u16 dbuf
    const int kvb = wave * 256;
    const u16* kbase = kk_ + (size_t)(b * 1024 + kvb) * 1024 + h * 64 + sgsw * 8;
    gload16(kbase + (size_t)srow8 * 1024, kw);
    gload16(kbase + (size_t)(8 + srow8) * 1024, kw + 512);
    for (int c = 0; c < 16; ++c) {
      if (c < 15) {
        const u16* nsrc = kbase + (size_t)((c + 1) * 16 + srow8) * 1024;
        u16* ndst = kw + ((c + 1) & 1) * 1024;
        gload16(nsrc, ndst);
        gload16(nsrc + 8 * 1024, ndst + 512);
        asm volatile("s_waitcnt vmcnt(2)" ::: "memory");
      } else {
        asm volatile("s_waitcnt vmcnt(0)" ::: "memory");
      }
      __builtin_amdgcn_sched_barrier(0);
      const u16* kb = kw + (c & 1) * 1024;
      const int r = l15;
      bf16x8 k0 = *(const bf16x8*)(kb + r * 64 + ((l4 ^ (r & 7)) << 3));
      bf16x8 k1 = *(const bf16x8*)(kb + r * 64 + (((4 + l4) ^ (r & 7)) << 3));
      f32x4 cc = {};
      cc = mfma16(k0, qf0, cc);
      cc = mfma16(k1, qf1, cc);
      const int c4 = kvb + c * 16 + l4 * 4;
      u16x4 pk;
      pk.x = bf(cc[0]); pk.y = bf(cc[1]); pk.z = bf(cc[2]); pk.w = bf(cc[3]);
      *(u16x4*)(sc + l15 * 1024 + (c4 ^ ((l15 & 7) << 3))) = pk;
    }
  }
  __syncthreads();   // sc complete; kst dead (P1 layout)

  // PV waves (0-1) prefetch their V chunk 0 (4 x 1KB) -> lands during softmax.
  const u16* vbase2 = vt + (size_t)(b * 1024 + h * 64 + wave * 32 + srow8) * 1024 + sgsw * 8;
  u16* const kw3 = kst + wave * 4096;  // 2 x 2048 u16 dbuf (waves 0-1 only)
  if (wave < 2) {
#pragma unroll
    for (int i = 0; i < 4; ++i)
      gload16(vbase2 + (size_t)(i * 8) * 1024, kw3 + i * 512);
  }

  // ---- P2: softmax + pbb add (all waves) ----
  const int r2 = tid >> 4;
  const int l2 = tid & 15;
  {
    const int rx = (r2 & 7) << 3;
    u16* rowp = sc + r2 * 1024;
    const u16* pbrow = pbb + (size_t)(q0 + r2) * 1024 + l2 * 8;
    bf16x8 R[8];
#pragma unroll
    for (int g = 0; g < 8; ++g) {
      bf16x8 v = *(const bf16x8*)(rowp + ((g * 128 + l2 * 8) ^ rx));
      bf16x8 pv = *(const bf16x8*)(pbrow + g * 128);
      bf16x8 s;
#pragma unroll
      for (int j = 0; j < 8; ++j) s[j] = (short)bf(b2f(v[j]) + b2f(pv[j]));
      R[g] = s;
    }
    float mx = -3e38f;
#pragma unroll
    for (int g = 0; g < 8; ++g)
#pragma unroll
      for (int j = 0; j < 8; ++j) mx = fmaxf(mx, b2f(R[g][j]));
#pragma unroll
    for (int o = 1; o < 16; o <<= 1) mx = fmaxf(mx, __shfl_xor(mx, o));
    float sum = 0.f;
#pragma unroll
    for (int g = 0; g < 8; ++g) {
      bf16x8 e;
#pragma unroll
      for (int j = 0; j < 8; ++j) {
        float t = exp2f(b2f(R[g][j]) - mx);
        sum += t;
        e[j] = (short)bf(t);
      }
      *(bf16x8*)(rowp + ((g * 128 + l2 * 8) ^ rx)) = e;  // unnormalized exp
    }
#pragma unroll
    for (int o = 1; o < 16; o <<= 1) sum += __shfl_xor(sum, o);
    if (l2 == 0) invbuf[r2] = 1.f / sum;
  }
  __syncthreads();   // exp-P + invbuf visible; PV waves' V0 drained

  if (wave < 2) {
    // ---- PV waves: O = P.V^T over 32 d-rows, 16 chunks of 64 kv ----
    f32x4 oacc[2] = {};
    for (int c = 0; c < 16; ++c) {
      if (c < 15) {
        const u16* nsrc = vbase2 + (c + 1) * 64;
        u16* ndst = kw3 + ((c + 1) & 1) * 2048;
#pragma unroll
        for (int i = 0; i < 4; ++i)
          gload16(nsrc + (size_t)(i * 8) * 1024, ndst + i * 512);
        asm volatile("s_waitcnt vmcnt(4)" ::: "memory");
      } else {
        asm volatile("s_waitcnt vmcnt(0)" ::: "memory");
      }
      __builtin_amdgcn_sched_barrier(0);
      const u16* vb = kw3 + (c & 1) * 2048;
#pragma unroll
      for (int ks = 0; ks < 2; ++ks) {
        const int gg = ks * 4 + l4;
        const int e = c * 64 + ks * 32 + l4 * 8;
        bf16x8 pf = *(const bf16x8*)(sc + l15 * 1024 + (e ^ ((l15 & 7) << 3)));
#pragma unroll
        for (int dg = 0; dg < 2; ++dg) {
          const int vr = dg * 16 + l15;
          bf16x8 vf = *(const bf16x8*)(vb + vr * 64 + ((gg ^ (vr & 7)) << 3));
          oacc[dg] = mfma16(pf, vf, oacc[dg]);
        }
      }
    }
#pragma unroll
    for (int dg = 0; dg < 2; ++dg)
#pragma unroll
      for (int i = 0; i < 4; ++i) {
        float iv = invbuf[l4 * 4 + i];
        aout[(size_t)(b * 1024 + q0 + l4 * 4 + i) * 1024 + h * 64 + wave * 32 +
             dg * 16 + l15] = bf(oacc[dg][i] * iv);
      }
  } else {
    // ---- store waves: attn_out NT full-line stores (overlaps PV) ----
    const int tid2 = tid - 128;  // 0..127
#pragma unroll
    for (int it = 0; it < 32; ++it) {
      const int row = it >> 1;
      const int col4 = (it & 1) * 128 + tid2;
      const int ebase = (col4 * 4) ^ ((row & 7) << 3);
      u16x4 p = *(const u16x4*)(sc + row * 1024 + ebase);
      const float iv = invbuf[row];
      f32x4 w;
      w[0] = b2f((short)p.x) * iv;
      w[1] = b2f((short)p.y) * iv;
      w[2] = b2f((short)p.z) * iv;
      w[3] = b2f((short)p.w) * iv;
      __builtin_nontemporal_store(
          w, (f32x4*)(attn_out + ((size_t)bh * 1024 + q0 + row) * 1024 + col4 * 4));
    }
  }
}

// ---------------- LayerNorm: one wave per row ----------------
__global__ __launch_bounds__(256) void k_ln(const float* __restrict__ y,
                                            const float* __restrict__ g,
                                            const float* __restrict__ be,
                                            float* __restrict__ o) {
  const int lane = threadIdx.x & 63;
  const int wave = threadIdx.x >> 6;
  size_t row = (size_t)blockIdx.x * 4 + wave;
  const float* yr = y + row * 1024;
  float4 v[4];
  float s = 0.f, sq = 0.f;
#pragma unroll
  for (int i = 0; i < 4; ++i) {
    v[i] = *(const float4*)(yr + i * 256 + lane * 4);
    s += v[i].x + v[i].y + v[i].z + v[i].w;
    sq += v[i].x * v[i].x + v[i].y * v[i].y + v[i].z * v[i].z + v[i].w * v[i].w;
  }
#pragma unroll
  for (int off = 1; off < 64; off <<= 1) {
    s += __shfl_xor(s, off);
    sq += __shfl_xor(sq, off);
  }
  float mu = s * (1.f / 1024.f);
  float var = sq * (1.f / 1024.f) - mu * mu;
  float rs = rsqrtf(fmaxf(var, 0.f) + 1e-5f);
  float* orow = o + row * 1024;
#pragma unroll
  for (int i = 0; i < 4; ++i) {
    int c = i * 256 + lane * 4;
    float4 gg = *(const float4*)(g + c);
    float4 bb = *(const float4*)(be + c);
    float4 rr;
    rr.x = (v[i].x - mu) * rs * gg.x + bb.x;
    rr.y = (v[i].y - mu) * rs * gg.y + bb.y;
    rr.z = (v[i].z - mu) * rs * gg.z + bb.z;
    rr.w = (v[i].w - mu) * rs * gg.w + bb.w;
    *(float4*)(orow + c) = rr;
  }
}

extern "C" void kernel_launch(void* const* d_in, const int* in_sizes, int n_in,
                              void* d_out, int out_size, void* d_ws, size_t ws_size,
                              hipStream_t stream) {
  const float* x = (const float*)d_in[0];
  const float* Wq = (const float*)d_in[1];
  const float* bq = (const float*)d_in[2];
  const float* Wk = (const float*)d_in[3];
  const float* bk = (const float*)d_in[4];
  const float* Wv = (const float*)d_in[5];
  const float* bv = (const float*)d_in[6];
  const float* pb = (const float*)d_in[7];
  const float* Wo = (const float*)d_in[8];
  const float* bo = (const float*)d_in[9];
  const float* gamma = (const float*)d_in[10];
  const float* beta = (const float*)d_in[11];

  char* ws = (char*)d_ws;
  u16* xb = (u16*)(ws);
  u16* aows = (u16*)(ws);
  u16* wqT = (u16*)(ws + (16u << 20));
  u16* wkT = (u16*)(ws + (18u << 20));
  u16* wvT = (u16*)(ws + (20u << 20));
  u16* woT = (u16*)(ws + (22u << 20));
  u16* qws = (u16*)(ws + (24u << 20));
  u16* kws = (u16*)(ws + (40u << 20));
  u16* vtws = (u16*)(ws + (56u << 20));
  float* yws = (float*)(ws + (72u << 20));
  u16* pbb = (u16*)(ws + (72u << 20));  // overlays yws head; dead before gemm_o writes

  float* out_ln = (float*)d_out;
  float* out_attn = out_ln + (size_t)Mm * Dd;

  k_prep<<<13312, 256, 0, stream>>>(x, xb, pb, pbb, Wq, Wk, Wv, Wo,
                                    wqT, wkT, wvT, woT);
  k_gemm_qkv<<<1536, 256, 0, stream>>>(xb, wqT, wkT, wvT,
                                       bq, bk, bv, qws, kws, vtws);
  k_attn<<<8192, 256, 0, stream>>>(qws, kws, vtws, pbb, out_attn, aows);
  k_gemm_o<<<512, 256, 0, stream>>>(aows, woT, bo, x, yws);
  k_ln<<<2048, 256, 0, stream>>>(yws, gamma, beta, out_ln);
}